// Round 2
// baseline (631.080 us; speedup 1.0000x reference)
//
#include <hip/hip_runtime.h>
#include <hip/hip_bf16.h>

// ---------- types ----------
typedef __attribute__((ext_vector_type(8))) short bf8_t;   // 8 bf16 in 4 VGPRs
typedef __attribute__((ext_vector_type(4))) float f4_t;    // MFMA accumulator

#define MFMA16(a, b, c) __builtin_amdgcn_mfma_f32_16x16x32_bf16((a), (b), (c), 0, 0, 0)

static __device__ inline unsigned short f2bf(float f) {
    unsigned int u = __float_as_uint(f);
    unsigned int r = 0x7fffu + ((u >> 16) & 1u);
    return (unsigned short)((u + r) >> 16);
}

// ---------- mask probe + additive-bias build (single block) ----------
// flag: 0 = int32 {0,1}, 1 = float32 {0,1.0f}, 2 = bytes
__global__ void k_bias(const void* __restrict__ maskp, float* __restrict__ fbias) {
    __shared__ int s_int, s_flt;
    const unsigned int* mw = (const unsigned int*)maskp;
    if (threadIdx.x == 0) { s_int = 1; s_flt = 1; }
    __syncthreads();
    int li = 1, lf = 1;
    for (int i = threadIdx.x; i < 2048; i += 1024) {
        unsigned int v = mw[i];
        if (v != 0u && v != 1u) li = 0;
        if (v != 0u && v != 0x3F800000u) lf = 0;
    }
    if (!li) atomicAnd(&s_int, 0);
    if (!lf) atomicAnd(&s_flt, 0);
    __syncthreads();
    const int flag = s_int ? 0 : (s_flt ? 1 : 2);
    const int*           mi = (const int*)maskp;
    const float*         mf = (const float*)maskp;
    const unsigned char* mb = (const unsigned char*)maskp;
    for (int i = threadIdx.x; i < 8192; i += 1024) {
        bool m = (flag == 0) ? (mi[i] != 0) : (flag == 1) ? (mf[i] != 0.0f) : (mb[i] != 0);
        fbias[i] = m ? -1e30f : 0.0f;
    }
}

// ---------- fp32 -> bf16 convert (x) ----------
__global__ void k_cvt(const float* __restrict__ x, unsigned short* __restrict__ xb, int n4) {
    int i = blockIdx.x * blockDim.x + threadIdx.x;
    if (i < n4) {
        float4 v = ((const float4*)x)[i];
        ushort4 o;
        o.x = f2bf(v.x); o.y = f2bf(v.y); o.z = f2bf(v.z); o.w = f2bf(v.w);
        ((ushort4*)xb)[i] = o;
    }
}

// ---------- W [K][N] fp32 -> WT [N][K] bf16 (4 matrices) ----------
__global__ void k_transw(const float* __restrict__ Wq, const float* __restrict__ Wk,
                         const float* __restrict__ Wv, const float* __restrict__ Wo,
                         unsigned short* __restrict__ WT) {
    __shared__ float tile[32][33];
    const float* W = (blockIdx.z == 0) ? Wq : (blockIdx.z == 1) ? Wk : (blockIdx.z == 2) ? Wv : Wo;
    unsigned short* out = WT + (size_t)blockIdx.z * 1024 * 1024;
    int n_r = blockIdx.x * 32 + threadIdx.x;
    int k_r = blockIdx.y * 32 + threadIdx.y;
    #pragma unroll
    for (int j = 0; j < 32; j += 8)
        tile[threadIdx.y + j][threadIdx.x] = W[(size_t)(k_r + j) * 1024 + n_r];
    __syncthreads();
    int k_w = blockIdx.y * 32 + threadIdx.x;
    int n_w = blockIdx.x * 32 + threadIdx.y;
    #pragma unroll
    for (int j = 0; j < 32; j += 8)
        out[(size_t)(n_w + j) * 1024 + k_w] = f2bf(tile[threadIdx.x][threadIdx.y + j]);
}

// ---------- GEMM: C[8192][1024] = A_bf16 @ WT^T (+bias) ----------
// MODE 0: bf16 out, [B,H,S,dh] layout, z selects Wq/Wk/Wv; z==0 scaled by 0.125*log2e.
// MODE 1: fp32 out [M][N] + bias.
template <int MODE>
__global__ __launch_bounds__(256) void k_gemm(
    const unsigned short* __restrict__ A,
    const unsigned short* __restrict__ WTb,
    const float* __restrict__ b0, const float* __restrict__ b1, const float* __restrict__ b2,
    void* __restrict__ outp)
{
    __shared__ unsigned short Als[128][40];
    __shared__ unsigned short Bls[128][40];
    const int tid  = threadIdx.x;
    const int lane = tid & 63;
    const int w    = tid >> 6;
    const int wr   = w >> 1, wc = w & 1;
    const int lg   = lane >> 4, lr = lane & 15;
    const int bm   = blockIdx.y * 128;
    const int bn   = blockIdx.x * 128;
    const unsigned short* WT = WTb + (MODE == 0 ? (size_t)blockIdx.z * (1024 * 1024) : 0);

    f4_t acc[4][4];
    const f4_t z4 = {0.f, 0.f, 0.f, 0.f};
    #pragma unroll
    for (int i = 0; i < 4; ++i)
        #pragma unroll
        for (int j = 0; j < 4; ++j) acc[i][j] = z4;

    const int srow = tid >> 2;
    const int scol = (tid & 3) * 8;

    for (int k0 = 0; k0 < 1024; k0 += 32) {
        __syncthreads();
        #pragma unroll
        for (int p = 0; p < 2; ++p) {
            int r = srow + p * 64;
            *(bf8_t*)(&Als[r][scol]) = *(const bf8_t*)(A  + (size_t)(bm + r) * 1024 + k0 + scol);
            *(bf8_t*)(&Bls[r][scol]) = *(const bf8_t*)(WT + (size_t)(bn + r) * 1024 + k0 + scol);
        }
        __syncthreads();

        bf8_t af[4], bfv[4];
        #pragma unroll
        for (int i = 0; i < 4; ++i) af[i]  = *(const bf8_t*)(&Als[wr * 64 + i * 16 + lr][lg * 8]);
        #pragma unroll
        for (int j = 0; j < 4; ++j) bfv[j] = *(const bf8_t*)(&Bls[wc * 64 + j * 16 + lr][lg * 8]);
        #pragma unroll
        for (int i = 0; i < 4; ++i)
            #pragma unroll
            for (int j = 0; j < 4; ++j)
                acc[i][j] = MFMA16(af[i], bfv[j], acc[i][j]);
    }

    if (MODE == 0) {
        unsigned short* O = (unsigned short*)outp + (size_t)blockIdx.z * (8192 * 1024);
        const float* bias = (blockIdx.z == 0) ? b0 : (blockIdx.z == 1) ? b1 : b2;
        const float sc = (blockIdx.z == 0) ? 0.18033688011112042f : 1.0f; // 0.125*log2(e)
        #pragma unroll
        for (int i = 0; i < 4; ++i)
            #pragma unroll
            for (int j = 0; j < 4; ++j)
                #pragma unroll
                for (int r = 0; r < 4; ++r) {
                    int row = bm + wr * 64 + i * 16 + lg * 4 + r;
                    int col = bn + wc * 64 + j * 16 + lr;
                    float v = (acc[i][j][r] + bias[col]) * sc;
                    int b = row >> 11, s = row & 2047, h = col >> 6, d = col & 63;
                    O[(((size_t)(b * 16 + h)) * 2048 + s) * 64 + d] = f2bf(v);
                }
    } else {
        float* O = (float*)outp;
        #pragma unroll
        for (int i = 0; i < 4; ++i)
            #pragma unroll
            for (int j = 0; j < 4; ++j)
                #pragma unroll
                for (int r = 0; r < 4; ++r) {
                    int row = bm + wr * 64 + i * 16 + lg * 4 + r;
                    int col = bn + wc * 64 + j * 16 + lr;
                    O[(size_t)row * 1024 + col] = acc[i][j][r] + b0[col];
                }
    }
}

// ---------- V [bh][s][d] -> VT [bh][d][s] ----------
__global__ __launch_bounds__(256) void k_vtrans(const unsigned short* __restrict__ V,
                                                unsigned short* __restrict__ VT) {
    __shared__ unsigned short t[64][72];
    const int bh = blockIdx.y;
    const int s0 = blockIdx.x * 64;
    const int tid = threadIdx.x;
    const int sr = tid >> 2;
    const int c0 = (tid & 3) * 16;
    const unsigned short* src = V + ((size_t)bh * 2048 + s0 + sr) * 64 + c0;
    bf8_t a = *(const bf8_t*)src;
    bf8_t bq = *(const bf8_t*)(src + 8);
    #pragma unroll
    for (int e = 0; e < 8; ++e) {
        t[c0 + e][sr]     = (unsigned short)a[e];
        t[c0 + 8 + e][sr] = (unsigned short)bq[e];
    }
    __syncthreads();
    unsigned short* dst = VT + ((size_t)bh * 64 + sr) * 2048 + s0 + c0;
    *(bf8_t*)dst       = *(const bf8_t*)&t[sr][c0];
    *(bf8_t*)(dst + 8) = *(const bf8_t*)&t[sr][c0 + 8];
}

// ---------- flash attention, swapped-QK^T, KBLK=64, barrier-free ----------
// grid (S/64, B*H), 4 waves x 16 q-rows. Q pre-scaled by 0.125*log2e.
__global__ __launch_bounds__(256) void k_attn(
    const unsigned short* __restrict__ Q,    // [64][2048][64]
    const unsigned short* __restrict__ K,    // [64][2048][64]
    const unsigned short* __restrict__ VT,   // [64][64][2048]
    const float* __restrict__ fbias,         // [4][2048] 0/-1e30
    unsigned short* __restrict__ O)          // [8192][1024]
{
    __shared__ unsigned short pls[4][16][72];   // per-wave P buffer (wave-local, no barriers)
    const int tid  = threadIdx.x;
    const int lane = tid & 63;
    const int w    = tid >> 6;
    const int lg   = lane >> 4, lr = lane & 15;
    const int bh   = blockIdx.y;
    const int b    = bh >> 4, h = bh & 15;
    const int q0   = blockIdx.x * 64 + w * 16;
    const size_t base = (size_t)bh * (2048 * 64);

    // Q fragments (B-operand): lane holds Q[q=lr][dh=lg*8..]
    const bf8_t qf0 = *(const bf8_t*)(Q + base + (size_t)(q0 + lr) * 64 + lg * 8);
    const bf8_t qf1 = *(const bf8_t*)(Q + base + (size_t)(q0 + lr) * 64 + 32 + lg * 8);

    const f4_t z4 = {0.f, 0.f, 0.f, 0.f};
    f4_t oacc[4] = {z4, z4, z4, z4};
    float mrow = -1e30f;   // running max for q = lr (already in log2 domain)
    float lsum = 0.0f;     // running denom for q = lr

    const unsigned short* Kp = K + base + (size_t)lr * 64 + lg * 8;
    const unsigned short* Vp = VT + (size_t)bh * (64 * 2048) + (size_t)lr * 2048 + lg * 8;
    const float* fb = fbias + b * 2048 + lg * 4;
    unsigned short* pw = &pls[w][lr][0];
    const unsigned short* pr = &pls[w][lr][lg * 8];

    for (int k0 = 0; k0 < 2048; k0 += 64) {
        // --- S^T = K · Q^T : D[key][q], col=lane&15 = q, row = lg*4+r = key ---
        f4_t s[4];
        #pragma unroll
        for (int mf = 0; mf < 4; ++mf) {
            const unsigned short* kr = Kp + (size_t)(k0 + mf * 16) * 64;
            bf8_t kf0 = *(const bf8_t*)kr;
            bf8_t kf1 = *(const bf8_t*)(kr + 32);
            f4_t zz = z4;
            zz = MFMA16(kf0, qf0, zz);
            zz = MFMA16(kf1, qf1, zz);
            s[mf] = zz;
        }
        // --- additive key mask ---
        #pragma unroll
        for (int mf = 0; mf < 4; ++mf) {
            float4 bv = *(const float4*)(fb + k0 + mf * 16);
            s[mf][0] += bv.x; s[mf][1] += bv.y; s[mf][2] += bv.z; s[mf][3] += bv.w;
        }
        // --- row max: 15 in-reg + 2 shuffles ---
        float m0 = fmaxf(fmaxf(s[0][0], s[0][1]), fmaxf(s[0][2], s[0][3]));
        float m1 = fmaxf(fmaxf(s[1][0], s[1][1]), fmaxf(s[1][2], s[1][3]));
        float m2 = fmaxf(fmaxf(s[2][0], s[2][1]), fmaxf(s[2][2], s[2][3]));
        float m3 = fmaxf(fmaxf(s[3][0], s[3][1]), fmaxf(s[3][2], s[3][3]));
        float smax = fmaxf(fmaxf(m0, m1), fmaxf(m2, m3));
        smax = fmaxf(smax, __shfl_xor(smax, 16));
        smax = fmaxf(smax, __shfl_xor(smax, 32));
        // --- defer-max: rescale only if some row's max grew ---
        if (__any(smax > mrow)) {
            float mnew = fmaxf(mrow, smax);
            float c = exp2f(mrow - mnew);
            mrow = mnew;
            lsum *= c;
            #pragma unroll
            for (int r = 0; r < 4; ++r) {
                float cr = __shfl(c, lg * 4 + r);
                oacc[0][r] *= cr; oacc[1][r] *= cr; oacc[2][r] *= cr; oacc[3][r] *= cr;
            }
        }
        // --- P = exp2(S - m), accumulate denom, stash bf16 P (wave-local LDS) ---
        float bsum = 0.0f;
        #pragma unroll
        for (int mf = 0; mf < 4; ++mf) {
            ushort4 pk;
            float p0 = exp2f(s[mf][0] - mrow);
            float p1 = exp2f(s[mf][1] - mrow);
            float p2 = exp2f(s[mf][2] - mrow);
            float p3 = exp2f(s[mf][3] - mrow);
            bsum += (p0 + p1) + (p2 + p3);
            pk.x = f2bf(p0); pk.y = f2bf(p1); pk.z = f2bf(p2); pk.w = f2bf(p3);
            *(ushort4*)(pw + mf * 16 + lg * 4) = pk;
        }
        bsum += __shfl_xor(bsum, 16);
        bsum += __shfl_xor(bsum, 32);
        lsum += bsum;
        // --- PV: A = P[q][key] from LDS, B = V^T[d][key] from global ---
        bf8_t pa0 = *(const bf8_t*)pr;
        bf8_t pa1 = *(const bf8_t*)(pr + 32);
        #pragma unroll
        for (int nf = 0; nf < 4; ++nf) {
            const unsigned short* vr = Vp + (size_t)(nf * 16) * 2048 + k0;
            bf8_t vf0 = *(const bf8_t*)vr;
            bf8_t vf1 = *(const bf8_t*)(vr + 32);
            oacc[nf] = MFMA16(pa0, vf0, oacc[nf]);
            oacc[nf] = MFMA16(pa1, vf1, oacc[nf]);
        }
    }

    // --- normalize + write [B,S,D] bf16 ---
    #pragma unroll
    for (int r = 0; r < 4; ++r) {
        float ls = __shfl(lsum, lg * 4 + r);
        float inv = 1.0f / ls;
        int srow = q0 + lg * 4 + r;
        size_t ob = ((size_t)(b * 2048 + srow)) * 1024 + h * 64;
        #pragma unroll
        for (int nf = 0; nf < 4; ++nf)
            O[ob + nf * 16 + lr] = f2bf(oacc[nf][r] * inv);
    }
}

// ---------- launch ----------
extern "C" void kernel_launch(void* const* d_in, const int* in_sizes, int n_in,
                              void* d_out, int out_size, void* d_ws, size_t ws_size,
                              hipStream_t stream) {
    const float* x  = (const float*)d_in[0];
    const void*  mask = d_in[1];
    const float* Wq = (const float*)d_in[2];
    const float* bq = (const float*)d_in[3];
    const float* Wk = (const float*)d_in[4];
    const float* bk = (const float*)d_in[5];
    const float* Wv = (const float*)d_in[6];
    const float* bv = (const float*)d_in[7];
    const float* Wo = (const float*)d_in[8];
    const float* bo = (const float*)d_in[9];

    char* ws = (char*)d_ws;
    float*          fbias = (float*)(ws + 1024);                          // 32 KiB
    unsigned short* xb    = (unsigned short*)(ws + 65536);                // 16 MiB (reused as VT)
    unsigned short* wT    = (unsigned short*)(ws + 65536 + 16777216);     // 8 MiB
    unsigned short* qkv   = (unsigned short*)(ws + 65536 + 25165824);     // 48 MiB
    unsigned short* attnb = (unsigned short*)(ws + 65536 + 75497472);     // 16 MiB

    unsigned short* Qb = qkv;
    unsigned short* Kb = qkv + 8388608;
    unsigned short* Vb = qkv + 16777216;
    unsigned short* VT = xb;   // xb is dead after the QKV GEMM

    k_bias<<<1, 1024, 0, stream>>>(mask, fbias);
    k_cvt<<<8192, 256, 0, stream>>>(x, xb, 2097152);
    k_transw<<<dim3(32, 32, 4), dim3(32, 8), 0, stream>>>(Wq, Wk, Wv, Wo, wT);
    k_gemm<0><<<dim3(8, 64, 3), 256, 0, stream>>>(xb, wT, bq, bk, bv, (void*)qkv);
    k_vtrans<<<dim3(32, 64), 256, 0, stream>>>(Vb, VT);
    k_attn<<<dim3(32, 64), 256, 0, stream>>>(Qb, Kb, VT, fbias, attnb);
    k_gemm<1><<<dim3(8, 64, 1), 256, 0, stream>>>(attnb, wT + 3145728, bo, bo, bo, d_out);
}

// Round 3
// 607.006 us; speedup vs baseline: 1.0397x; 1.0397x over previous
//
#include <hip/hip_runtime.h>
#include <hip/hip_bf16.h>

// ---------- types ----------
typedef __attribute__((ext_vector_type(8))) short bf8_t;   // 8 bf16 in 4 VGPRs
typedef __attribute__((ext_vector_type(4))) float f4_t;    // MFMA accumulator

#define MFMA16(a, b, c) __builtin_amdgcn_mfma_f32_16x16x32_bf16((a), (b), (c), 0, 0, 0)

static __device__ inline unsigned short f2bf(float f) {
    unsigned int u = __float_as_uint(f);
    unsigned int r = 0x7fffu + ((u >> 16) & 1u);
    return (unsigned short)((u + r) >> 16);
}

// ---------- mask probe + additive-bias build (single block) ----------
__global__ void k_bias(const void* __restrict__ maskp, float* __restrict__ fbias) {
    __shared__ int s_int, s_flt;
    const unsigned int* mw = (const unsigned int*)maskp;
    if (threadIdx.x == 0) { s_int = 1; s_flt = 1; }
    __syncthreads();
    int li = 1, lf = 1;
    for (int i = threadIdx.x; i < 2048; i += 1024) {
        unsigned int v = mw[i];
        if (v != 0u && v != 1u) li = 0;
        if (v != 0u && v != 0x3F800000u) lf = 0;
    }
    if (!li) atomicAnd(&s_int, 0);
    if (!lf) atomicAnd(&s_flt, 0);
    __syncthreads();
    const int flag = s_int ? 0 : (s_flt ? 1 : 2);
    const int*           mi = (const int*)maskp;
    const float*         mf = (const float*)maskp;
    const unsigned char* mb = (const unsigned char*)maskp;
    for (int i = threadIdx.x; i < 8192; i += 1024) {
        bool m = (flag == 0) ? (mi[i] != 0) : (flag == 1) ? (mf[i] != 0.0f) : (mb[i] != 0);
        fbias[i] = m ? -1e30f : 0.0f;
    }
}

// ---------- fp32 -> bf16 convert (x) ----------
__global__ void k_cvt(const float* __restrict__ x, unsigned short* __restrict__ xb, int n4) {
    int i = blockIdx.x * blockDim.x + threadIdx.x;
    if (i < n4) {
        float4 v = ((const float4*)x)[i];
        ushort4 o;
        o.x = f2bf(v.x); o.y = f2bf(v.y); o.z = f2bf(v.z); o.w = f2bf(v.w);
        ((ushort4*)xb)[i] = o;
    }
}

// ---------- W [K][N] fp32 -> WT [N][K] bf16 (4 matrices) ----------
__global__ void k_transw(const float* __restrict__ Wq, const float* __restrict__ Wk,
                         const float* __restrict__ Wv, const float* __restrict__ Wo,
                         unsigned short* __restrict__ WT) {
    __shared__ float tile[32][33];
    const float* W = (blockIdx.z == 0) ? Wq : (blockIdx.z == 1) ? Wk : (blockIdx.z == 2) ? Wv : Wo;
    unsigned short* out = WT + (size_t)blockIdx.z * 1024 * 1024;
    int n_r = blockIdx.x * 32 + threadIdx.x;
    int k_r = blockIdx.y * 32 + threadIdx.y;
    #pragma unroll
    for (int j = 0; j < 32; j += 8)
        tile[threadIdx.y + j][threadIdx.x] = W[(size_t)(k_r + j) * 1024 + n_r];
    __syncthreads();
    int k_w = blockIdx.y * 32 + threadIdx.x;
    int n_w = blockIdx.x * 32 + threadIdx.y;
    #pragma unroll
    for (int j = 0; j < 32; j += 8)
        out[(size_t)(n_w + j) * 1024 + k_w] = f2bf(tile[threadIdx.x][threadIdx.y + j]);
}

// ---------- GEMM: C[8192][1024] = A_bf16 @ WT^T (+bias) ----------
template <int MODE>
__global__ __launch_bounds__(256) void k_gemm(
    const unsigned short* __restrict__ A,
    const unsigned short* __restrict__ WTb,
    const float* __restrict__ b0, const float* __restrict__ b1, const float* __restrict__ b2,
    void* __restrict__ outp)
{
    __shared__ unsigned short Als[128][40];
    __shared__ unsigned short Bls[128][40];
    const int tid  = threadIdx.x;
    const int lane = tid & 63;
    const int w    = tid >> 6;
    const int wr   = w >> 1, wc = w & 1;
    const int lg   = lane >> 4, lr = lane & 15;
    const int bm   = blockIdx.y * 128;
    const int bn   = blockIdx.x * 128;
    const unsigned short* WT = WTb + (MODE == 0 ? (size_t)blockIdx.z * (1024 * 1024) : 0);

    f4_t acc[4][4];
    const f4_t z4 = {0.f, 0.f, 0.f, 0.f};
    #pragma unroll
    for (int i = 0; i < 4; ++i)
        #pragma unroll
        for (int j = 0; j < 4; ++j) acc[i][j] = z4;

    const int srow = tid >> 2;
    const int scol = (tid & 3) * 8;

    for (int k0 = 0; k0 < 1024; k0 += 32) {
        __syncthreads();
        #pragma unroll
        for (int p = 0; p < 2; ++p) {
            int r = srow + p * 64;
            *(bf8_t*)(&Als[r][scol]) = *(const bf8_t*)(A  + (size_t)(bm + r) * 1024 + k0 + scol);
            *(bf8_t*)(&Bls[r][scol]) = *(const bf8_t*)(WT + (size_t)(bn + r) * 1024 + k0 + scol);
        }
        __syncthreads();

        bf8_t af[4], bfv[4];
        #pragma unroll
        for (int i = 0; i < 4; ++i) af[i]  = *(const bf8_t*)(&Als[wr * 64 + i * 16 + lr][lg * 8]);
        #pragma unroll
        for (int j = 0; j < 4; ++j) bfv[j] = *(const bf8_t*)(&Bls[wc * 64 + j * 16 + lr][lg * 8]);
        #pragma unroll
        for (int i = 0; i < 4; ++i)
            #pragma unroll
            for (int j = 0; j < 4; ++j)
                acc[i][j] = MFMA16(af[i], bfv[j], acc[i][j]);
    }

    if (MODE == 0) {
        unsigned short* O = (unsigned short*)outp + (size_t)blockIdx.z * (8192 * 1024);
        const float* bias = (blockIdx.z == 0) ? b0 : (blockIdx.z == 1) ? b1 : b2;
        const float sc = (blockIdx.z == 0) ? 0.18033688011112042f : 1.0f; // 0.125*log2(e)
        #pragma unroll
        for (int i = 0; i < 4; ++i)
            #pragma unroll
            for (int j = 0; j < 4; ++j)
                #pragma unroll
                for (int r = 0; r < 4; ++r) {
                    int row = bm + wr * 64 + i * 16 + lg * 4 + r;
                    int col = bn + wc * 64 + j * 16 + lr;
                    float v = (acc[i][j][r] + bias[col]) * sc;
                    int b = row >> 11, s = row & 2047, h = col >> 6, d = col & 63;
                    O[(((size_t)(b * 16 + h)) * 2048 + s) * 64 + d] = f2bf(v);
                }
    } else {
        float* O = (float*)outp;
        #pragma unroll
        for (int i = 0; i < 4; ++i)
            #pragma unroll
            for (int j = 0; j < 4; ++j)
                #pragma unroll
                for (int r = 0; r < 4; ++r) {
                    int row = bm + wr * 64 + i * 16 + lg * 4 + r;
                    int col = bn + wc * 64 + j * 16 + lr;
                    O[(size_t)row * 1024 + col] = acc[i][j][r] + b0[col];
                }
    }
}

// ---------- V [bh][s][d] -> VT [bh][d][s] ----------
__global__ __launch_bounds__(256) void k_vtrans(const unsigned short* __restrict__ V,
                                                unsigned short* __restrict__ VT) {
    __shared__ unsigned short t[64][72];
    const int bh = blockIdx.y;
    const int s0 = blockIdx.x * 64;
    const int tid = threadIdx.x;
    const int sr = tid >> 2;
    const int c0 = (tid & 3) * 16;
    const unsigned short* src = V + ((size_t)bh * 2048 + s0 + sr) * 64 + c0;
    bf8_t a = *(const bf8_t*)src;
    bf8_t bq = *(const bf8_t*)(src + 8);
    #pragma unroll
    for (int e = 0; e < 8; ++e) {
        t[c0 + e][sr]     = (unsigned short)a[e];
        t[c0 + 8 + e][sr] = (unsigned short)bq[e];
    }
    __syncthreads();
    unsigned short* dst = VT + ((size_t)bh * 64 + sr) * 2048 + s0 + c0;
    *(bf8_t*)dst       = *(const bf8_t*)&t[sr][c0];
    *(bf8_t*)(dst + 8) = *(const bf8_t*)&t[sr][c0 + 8];
}

// ---------- flash attention: reg-pipelined K, early V, XCD-grouped heads ----------
// grid 2048 x 256. 4 waves x 16 q-rows, KBLK=64. Q pre-scaled by 0.125*log2e.
__global__ __launch_bounds__(256, 1) void k_attn(
    const unsigned short* __restrict__ Q,    // [64][2048][64]
    const unsigned short* __restrict__ K,    // [64][2048][64]
    const unsigned short* __restrict__ VT,   // [64][64][2048]
    const float* __restrict__ fbias,         // [4][2048] 0/-1e30
    unsigned short* __restrict__ O)          // [8192][1024]
{
    __shared__ float sbias[2048];
    __shared__ unsigned short pls[4][16][72];
    const int tid  = threadIdx.x;
    const int lane = tid & 63;
    const int w    = tid >> 6;
    const int lg   = lane >> 4, lr = lane & 15;

    // XCD-bijective swizzle: XCD (id%8) owns heads [xcd*8, xcd*8+8) -> 4MB L2 set
    const int id  = blockIdx.x;
    const int bh  = (id & 7) * 8 + ((id >> 3) & 7);
    const int qt  = id >> 6;                  // 0..31
    const int b   = bh >> 4, h = bh & 15;
    const int q0  = qt * 64 + w * 16;
    const size_t base = (size_t)bh * (2048 * 64);

    // stage mask bias row for this batch into LDS (single barrier in kernel)
    {
        const float4* src = (const float4*)(fbias + b * 2048);
        float4* dst = (float4*)sbias;
        for (int i = tid; i < 512; i += 256) dst[i] = src[i];
    }
    __syncthreads();

    const bf8_t qf0 = *(const bf8_t*)(Q + base + (size_t)(q0 + lr) * 64 + lg * 8);
    const bf8_t qf1 = *(const bf8_t*)(Q + base + (size_t)(q0 + lr) * 64 + 32 + lg * 8);

    const f4_t z4 = {0.f, 0.f, 0.f, 0.f};
    f4_t oacc[4] = {z4, z4, z4, z4};
    float mrow = -1e30f;
    float lsum = 0.0f;

    const unsigned short* Krow = K + base + (size_t)lr * 64 + lg * 8;
    const unsigned short* Vrow = VT + (size_t)bh * (64 * 2048) + (size_t)lr * 2048 + lg * 8;
    unsigned short* pw = &pls[w][lr][0];
    const unsigned short* pr = &pls[w][lr][lg * 8];
    const int lg4 = lg * 4;

    bf8_t kA[4][2], kB[4][2];
    #pragma unroll
    for (int mf = 0; mf < 4; ++mf) {
        kA[mf][0] = *(const bf8_t*)(Krow + (size_t)(mf * 16) * 64);
        kA[mf][1] = *(const bf8_t*)(Krow + (size_t)(mf * 16) * 64 + 32);
    }

    auto step = [&](bf8_t (&kc)[4][2], bf8_t (&kn)[4][2], int k0) {
        // issue V(t) loads now; consumed after softmax (~600cy of cover)
        bf8_t vf[4][2];
        #pragma unroll
        for (int nf = 0; nf < 4; ++nf) {
            vf[nf][0] = *(const bf8_t*)(Vrow + (size_t)(nf * 16) * 2048 + k0);
            vf[nf][1] = *(const bf8_t*)(Vrow + (size_t)(nf * 16) * 2048 + k0 + 32);
        }
        // issue K(t+1) loads (register double-buffer; 8KB overread at end is benign)
        #pragma unroll
        for (int mf = 0; mf < 4; ++mf) {
            kn[mf][0] = *(const bf8_t*)(Krow + (size_t)(k0 + 64 + mf * 16) * 64);
            kn[mf][1] = *(const bf8_t*)(Krow + (size_t)(k0 + 64 + mf * 16) * 64 + 32);
        }
        // S^T = K·Q^T : lane holds S[key=lg*4+r][q=lr]
        f4_t s[4];
        #pragma unroll
        for (int mf = 0; mf < 4; ++mf) {
            f4_t zz = z4;
            zz = MFMA16(kc[mf][0], qf0, zz);
            zz = MFMA16(kc[mf][1], qf1, zz);
            s[mf] = zz;
        }
        // additive key mask from LDS
        #pragma unroll
        for (int mf = 0; mf < 4; ++mf) {
            float4 bv = *(const float4*)&sbias[k0 + mf * 16 + lg4];
            s[mf][0] += bv.x; s[mf][1] += bv.y; s[mf][2] += bv.z; s[mf][3] += bv.w;
        }
        // row max: 15 in-reg + 2 shuffles
        float m0 = fmaxf(fmaxf(s[0][0], s[0][1]), fmaxf(s[0][2], s[0][3]));
        float m1 = fmaxf(fmaxf(s[1][0], s[1][1]), fmaxf(s[1][2], s[1][3]));
        float m2 = fmaxf(fmaxf(s[2][0], s[2][1]), fmaxf(s[2][2], s[2][3]));
        float m3 = fmaxf(fmaxf(s[3][0], s[3][1]), fmaxf(s[3][2], s[3][3]));
        float smax = fmaxf(fmaxf(m0, m1), fmaxf(m2, m3));
        smax = fmaxf(smax, __shfl_xor(smax, 16));
        smax = fmaxf(smax, __shfl_xor(smax, 32));
        // defer-max rescale
        if (__any(smax > mrow)) {
            float mnew = fmaxf(mrow, smax);
            float c = exp2f(mrow - mnew);
            mrow = mnew;
            lsum *= c;
            #pragma unroll
            for (int r = 0; r < 4; ++r) {
                float cr = __shfl(c, lg4 + r);
                oacc[0][r] *= cr; oacc[1][r] *= cr; oacc[2][r] *= cr; oacc[3][r] *= cr;
            }
        }
        // P = exp2(S - m); denom; stash bf16 P (wave-local LDS)
        float bsum = 0.0f;
        #pragma unroll
        for (int mf = 0; mf < 4; ++mf) {
            ushort4 pk;
            float p0 = exp2f(s[mf][0] - mrow);
            float p1 = exp2f(s[mf][1] - mrow);
            float p2 = exp2f(s[mf][2] - mrow);
            float p3 = exp2f(s[mf][3] - mrow);
            bsum += (p0 + p1) + (p2 + p3);
            pk.x = f2bf(p0); pk.y = f2bf(p1); pk.z = f2bf(p2); pk.w = f2bf(p3);
            *(ushort4*)(pw + mf * 16 + lg4) = pk;
        }
        bsum += __shfl_xor(bsum, 16);
        bsum += __shfl_xor(bsum, 32);
        lsum += bsum;
        // PV: A = P[q][key] from LDS, B = V^T[d][key] from registers
        bf8_t pa0 = *(const bf8_t*)pr;
        bf8_t pa1 = *(const bf8_t*)(pr + 32);
        #pragma unroll
        for (int nf = 0; nf < 4; ++nf) {
            oacc[nf] = MFMA16(pa0, vf[nf][0], oacc[nf]);
            oacc[nf] = MFMA16(pa1, vf[nf][1], oacc[nf]);
        }
    };

    for (int t = 0; t < 2048; t += 128) {
        step(kA, kB, t);
        step(kB, kA, t + 64);
    }

    // normalize + write [B,S,D] bf16
    #pragma unroll
    for (int r = 0; r < 4; ++r) {
        float ls = __shfl(lsum, lg4 + r);
        float inv = 1.0f / ls;
        int srow = q0 + lg4 + r;
        size_t ob = ((size_t)(b * 2048 + srow)) * 1024 + h * 64;
        #pragma unroll
        for (int nf = 0; nf < 4; ++nf)
            O[ob + nf * 16 + lr] = f2bf(oacc[nf][r] * inv);
    }
}

// ---------- launch ----------
extern "C" void kernel_launch(void* const* d_in, const int* in_sizes, int n_in,
                              void* d_out, int out_size, void* d_ws, size_t ws_size,
                              hipStream_t stream) {
    const float* x  = (const float*)d_in[0];
    const void*  mask = d_in[1];
    const float* Wq = (const float*)d_in[2];
    const float* bq = (const float*)d_in[3];
    const float* Wk = (const float*)d_in[4];
    const float* bk = (const float*)d_in[5];
    const float* Wv = (const float*)d_in[6];
    const float* bv = (const float*)d_in[7];
    const float* Wo = (const float*)d_in[8];
    const float* bo = (const float*)d_in[9];

    char* ws = (char*)d_ws;
    float*          fbias = (float*)(ws + 1024);
    unsigned short* xb    = (unsigned short*)(ws + 65536);                // 16 MiB (reused as VT)
    unsigned short* wT    = (unsigned short*)(ws + 65536 + 16777216);     // 8 MiB
    unsigned short* qkv   = (unsigned short*)(ws + 65536 + 25165824);     // 48 MiB
    unsigned short* attnb = (unsigned short*)(ws + 65536 + 75497472);     // 16 MiB

    unsigned short* Qb = qkv;
    unsigned short* Kb = qkv + 8388608;
    unsigned short* Vb = qkv + 16777216;
    unsigned short* VT = xb;   // xb dead after QKV GEMM

    k_bias<<<1, 1024, 0, stream>>>(mask, fbias);
    k_cvt<<<8192, 256, 0, stream>>>(x, xb, 2097152);
    k_transw<<<dim3(32, 32, 4), dim3(32, 8), 0, stream>>>(Wq, Wk, Wv, Wo, wT);
    k_gemm<0><<<dim3(8, 64, 3), 256, 0, stream>>>(xb, wT, bq, bk, bv, (void*)qkv);
    k_vtrans<<<dim3(32, 64), 256, 0, stream>>>(Vb, VT);
    k_attn<<<2048, 256, 0, stream>>>(Qb, Kb, VT, fbias, attnb);
    k_gemm<1><<<dim3(8, 64, 1), 256, 0, stream>>>(attnb, wT + 3145728, bo, bo, bo, d_out);
}